// Round 2
// baseline (416.009 us; speedup 1.0000x reference)
//
#include <hip/hip_runtime.h>
#include <hip/hip_bf16.h>

// GCNConv: out = D^{-1/2}(A+I)D^{-1/2} X W + b
// N=100000 nodes, E=1.6M edges, 128->128 feats. Inputs/outputs FLOAT32 (per
// reference dtypes; round-1 NaN came from misreading fp32 as bf16 — low
// mantissa halves decode as Inf/NaN bf16s). edge_index int32.
// Pipeline per launch:
//   K1 zero deg -> K2 count in-degree (atomics) -> K3/K4/K5 exclusive scan
//   K6 scatter edges into CSR adj -> K7 h = bf16(x)@bf16(W) via MFMA (fp32 acc,
//   h stored bf16, 25.6MB L2/L3-resident) -> K8 wave-per-node gather, fp32 out.

#define NIN 128
#define NOUT 128

typedef __attribute__((ext_vector_type(8))) short short8;   // 8 bf16 (4 VGPRs)
typedef __attribute__((ext_vector_type(4))) float f32x4;    // MFMA accumulator

__device__ __forceinline__ float bf2f(unsigned short u) {
    unsigned v = ((unsigned)u) << 16;
    return __uint_as_float(v);
}
__device__ __forceinline__ unsigned short f2bf(float f) {
    unsigned u = __float_as_uint(f);
    unsigned r = 0x7FFFu + ((u >> 16) & 1u);   // RNE
    return (unsigned short)((u + r) >> 16);
}

// ---------------- K1: zero degree ----------------
__global__ void k_zero_deg(int* __restrict__ deg, int N) {
    int i = blockIdx.x * 256 + threadIdx.x;
    if (i < N) deg[i] = 0;
}

// ---------------- K2: count in-degree over dst ----------------
__global__ void k_count(const int* __restrict__ ei, int* __restrict__ deg, int E) {
    int e = blockIdx.x * 256 + threadIdx.x;
    if (e < E) {
        int d = ei[E + e];   // edge_index[1][e]
        atomicAdd(&deg[d], 1);
    }
}

// ---------------- K3: per-block exclusive scan (256 elems) ----------------
__global__ void k_scan_block(const int* __restrict__ deg, int* __restrict__ row_off,
                             int* __restrict__ bsum, int N) {
    __shared__ int s[256];
    int i = blockIdx.x * 256 + threadIdx.x;
    int v = (i < N) ? deg[i] : 0;
    s[threadIdx.x] = v;
    __syncthreads();
    #pragma unroll
    for (int off = 1; off < 256; off <<= 1) {
        int t = (threadIdx.x >= off) ? s[threadIdx.x - off] : 0;
        __syncthreads();
        s[threadIdx.x] += t;
        __syncthreads();
    }
    if (i < N) row_off[i] = s[threadIdx.x] - v;   // exclusive
    if (threadIdx.x == 255) bsum[blockIdx.x] = s[255];
}

// ---------------- K4: scan block sums (single block, nb<=512) ----------------
__global__ void k_scan_top(int* __restrict__ bsum, int nb) {
    __shared__ int s[512];
    int v = (threadIdx.x < nb) ? bsum[threadIdx.x] : 0;
    s[threadIdx.x] = v;
    __syncthreads();
    #pragma unroll
    for (int off = 1; off < 512; off <<= 1) {
        int t = (threadIdx.x >= off) ? s[threadIdx.x - off] : 0;
        __syncthreads();
        s[threadIdx.x] += t;
        __syncthreads();
    }
    if (threadIdx.x < nb) bsum[threadIdx.x] = s[threadIdx.x] - v;   // exclusive
}

// ---------------- K5: finalize offsets, cursors, dinv ----------------
__global__ void k_finalize(int* __restrict__ row_off, int* __restrict__ cursor,
                           const int* __restrict__ bsum, const int* __restrict__ deg,
                           float* __restrict__ dinv, int N, int E) {
    int i = blockIdx.x * 256 + threadIdx.x;
    if (i < N) {
        int v = row_off[i] + bsum[i >> 8];
        row_off[i] = v;
        cursor[i] = v;
        dinv[i] = rsqrtf((float)(deg[i] + 1));   // +1 for self loop
    }
    if (i == 0) row_off[N] = E;
}

// ---------------- K6: scatter edges into CSR ----------------
__global__ void k_scatter(const int* __restrict__ ei, int* __restrict__ cursor,
                          int* __restrict__ adj, int E) {
    int e = blockIdx.x * 256 + threadIdx.x;
    if (e < E) {
        int s = ei[e];
        int d = ei[E + e];
        int pos = atomicAdd(&cursor[d], 1);
        adj[pos] = s;
    }
}

// ---------------- K7: h = bf16(x) @ bf16(W)  (MFMA, fp32 accum, bf16 h) ----------------
// Block = 256 thr = 4 waves; wave computes 16 nodes x 128 feats; block = 64 nodes.
#define WT_PITCH 136
__global__ __launch_bounds__(256) void k_gemm(const float* __restrict__ x,
                                              const float* __restrict__ W,
                                              unsigned short* __restrict__ h, int N) {
    __shared__ unsigned short Wt[128 * WT_PITCH];   // Wt[n][k] bf16, padded
    for (int idx = threadIdx.x; idx < NIN * NOUT; idx += 256) {
        int k = idx >> 7, n = idx & 127;
        Wt[n * WT_PITCH + k] = f2bf(W[idx]);
    }
    __syncthreads();

    int wave = threadIdx.x >> 6, lane = threadIdx.x & 63;
    int node_base = blockIdx.x * 64 + wave * 16;
    if (node_base >= N) return;            // N % 16 == 0 -> active waves are full

    int c = lane & 15, quad = lane >> 4;

    // A frag: A[m=lane&15][k=quad*8+j]; convert 8 floats -> 8 bf16 per frag
    short8 a[4];
    const float* xrow = x + (size_t)(node_base + c) * NIN + quad * 8;
    #pragma unroll
    for (int kt = 0; kt < 4; kt++) {
        short8 af;
        #pragma unroll
        for (int j = 0; j < 8; j++)
            af[j] = (short)f2bf(xrow[kt * 32 + j]);
        a[kt] = af;
    }

    f32x4 acc[8];
    #pragma unroll
    for (int nt = 0; nt < 8; nt++) acc[nt] = (f32x4)(0.0f);

    #pragma unroll
    for (int nt = 0; nt < 8; nt++) {
        const unsigned short* wp = &Wt[(nt * 16 + c) * WT_PITCH + quad * 8];
        #pragma unroll
        for (int kt = 0; kt < 4; kt++) {
            short8 bfrag = *(const short8*)(wp + kt * 32);  // B[k=quad*8+j][n=lane&15]
            acc[nt] = __builtin_amdgcn_mfma_f32_16x16x32_bf16(a[kt], bfrag, acc[nt], 0, 0, 0);
        }
    }

    // D: col = lane&15, row = quad*4 + reg
    #pragma unroll
    for (int nt = 0; nt < 8; nt++) {
        #pragma unroll
        for (int r = 0; r < 4; r++) {
            int node = node_base + quad * 4 + r;
            if (node < N)
                h[(size_t)node * NOUT + nt * 16 + c] = f2bf(acc[nt][r]);
        }
    }
}

// ---------------- K8: aggregate — one wave per destination node ----------------
__global__ __launch_bounds__(256) void k_agg(const unsigned short* __restrict__ h,
                                             const float* __restrict__ dinv,
                                             const int* __restrict__ row_off,
                                             const int* __restrict__ adj,
                                             const float* __restrict__ bias,
                                             float* __restrict__ out, int N) {
    int wave = threadIdx.x >> 6, lane = threadIdx.x & 63;
    int node = blockIdx.x * 4 + wave;
    if (node >= N) return;

    float dn = dinv[node];
    const uint* hrow_self = (const uint*)(h + (size_t)node * NOUT);
    uint pv = hrow_self[lane];                      // 2 bf16 feats per lane
    float sn = dn * dn;                             // self-loop norm
    float ax = bf2f((unsigned short)(pv & 0xFFFF)) * sn;
    float ay = bf2f((unsigned short)(pv >> 16)) * sn;

    int e0 = row_off[node], e1 = row_off[node + 1];
    int e = e0;
    for (; e + 1 < e1; e += 2) {                    // unroll x2 for MLP
        int s0 = adj[e], s1 = adj[e + 1];
        float w0 = dinv[s0] * dn, w1 = dinv[s1] * dn;
        uint v0 = ((const uint*)(h + (size_t)s0 * NOUT))[lane];
        uint v1 = ((const uint*)(h + (size_t)s1 * NOUT))[lane];
        ax += bf2f((unsigned short)(v0 & 0xFFFF)) * w0;
        ay += bf2f((unsigned short)(v0 >> 16)) * w0;
        ax += bf2f((unsigned short)(v1 & 0xFFFF)) * w1;
        ay += bf2f((unsigned short)(v1 >> 16)) * w1;
    }
    if (e < e1) {
        int s0 = adj[e];
        float w0 = dinv[s0] * dn;
        uint v0 = ((const uint*)(h + (size_t)s0 * NOUT))[lane];
        ax += bf2f((unsigned short)(v0 & 0xFFFF)) * w0;
        ay += bf2f((unsigned short)(v0 >> 16)) * w0;
    }

    ax += bias[2 * lane];
    ay += bias[2 * lane + 1];

    float2 o = make_float2(ax, ay);
    ((float2*)(out + (size_t)node * NOUT))[lane] = o;
}

// ---------------- launch ----------------
static inline size_t align256(size_t v) { return (v + 255) & ~(size_t)255; }

extern "C" void kernel_launch(void* const* d_in, const int* in_sizes, int n_in,
                              void* d_out, int out_size, void* d_ws, size_t ws_size,
                              hipStream_t stream) {
    const float* x  = (const float*)d_in[0];     // f32 [N,128]
    const int*   ei = (const int*)d_in[1];       // int32 [2,E]
    // d_in[2] = edge_attr (f32 [E]), ignored by reference
    const float* W  = (const float*)d_in[3];     // f32 [128,128]
    const float* b  = (const float*)d_in[4];     // f32 [128]
    float*       out = (float*)d_out;            // f32 [N,128]

    int N = in_sizes[0] / NIN;
    int E = in_sizes[1] / 2;
    int nb = (N + 255) / 256;   // scan blocks (391 <= 512)

    char* ws = (char*)d_ws;
    size_t o = 0;
    int*   deg     = (int*)(ws + o);   o += align256((size_t)N * 4);
    float* dinv    = (float*)(ws + o); o += align256((size_t)N * 4);
    int*   row_off = (int*)(ws + o);   o += align256((size_t)(N + 1) * 4);
    int*   cursor  = (int*)(ws + o);   o += align256((size_t)N * 4);
    int*   bsum    = (int*)(ws + o);   o += align256((size_t)512 * 4);
    int*   adj     = (int*)(ws + o);   o += align256((size_t)E * 4);
    unsigned short* h = (unsigned short*)(ws + o); o += align256((size_t)N * NOUT * 2);
    (void)ws_size; (void)n_in; (void)out_size;

    int gN = (N + 255) / 256;
    int gE = (E + 255) / 256;

    k_zero_deg<<<gN, 256, 0, stream>>>(deg, N);
    k_count<<<gE, 256, 0, stream>>>(ei, deg, E);
    k_scan_block<<<nb, 256, 0, stream>>>(deg, row_off, bsum, N);
    k_scan_top<<<1, 512, 0, stream>>>(bsum, nb);
    k_finalize<<<gN, 256, 0, stream>>>(row_off, cursor, bsum, deg, dinv, N, E);
    k_scatter<<<gE, 256, 0, stream>>>(ei, cursor, adj, E);
    k_gemm<<<(N + 63) / 64, 256, 0, stream>>>(x, W, h, N);
    k_agg<<<(N + 3) / 4, 256, 0, stream>>>(h, dinv, row_off, adj, b, out, N);
}

// Round 3
// 410.484 us; speedup vs baseline: 1.0135x; 1.0135x over previous
//
#include <hip/hip_runtime.h>
#include <hip/hip_bf16.h>

// GCNConv: out = D^{-1/2}(A+I)D^{-1/2} X W + b
// N=100000, E=1.6M, 128->128, fp32 in/out. Pipeline:
//   K1 zero deg -> K2 count in-degree -> K3/K4/K5 scan -> K6 scatter (atomicExch:
//   routes scattered 4B stores via the coherent atomic point to kill the 16x
//   partial-line writeback amplification seen in round 2) -> K7 h' = (x@W)*dinv
//   via MFMA (pre-scaled by src norm; bf16, L3-resident) -> K8 wave-per-node
//   gather: out[d] = dn*(sum h'[src] + h'[d]) + b.

#define NIN 128
#define NOUT 128

typedef __attribute__((ext_vector_type(8))) short short8;   // 8 bf16 (4 VGPRs)
typedef __attribute__((ext_vector_type(4))) float f32x4;    // MFMA accumulator

__device__ __forceinline__ float bf2f(unsigned short u) {
    unsigned v = ((unsigned)u) << 16;
    return __uint_as_float(v);
}
__device__ __forceinline__ unsigned short f2bf(float f) {
    unsigned u = __float_as_uint(f);
    unsigned r = 0x7FFFu + ((u >> 16) & 1u);   // RNE
    return (unsigned short)((u + r) >> 16);
}

// ---------------- K1: zero degree ----------------
__global__ void k_zero_deg(int* __restrict__ deg, int N) {
    int i = blockIdx.x * 256 + threadIdx.x;
    if (i < N) deg[i] = 0;
}

// ---------------- K2: count in-degree over dst ----------------
__global__ void k_count(const int* __restrict__ ei, int* __restrict__ deg, int E) {
    int e = blockIdx.x * 256 + threadIdx.x;
    if (e < E) {
        int d = ei[E + e];   // edge_index[1][e]
        atomicAdd(&deg[d], 1);
    }
}

// ---------------- K3: per-block exclusive scan (256 elems) ----------------
__global__ void k_scan_block(const int* __restrict__ deg, int* __restrict__ row_off,
                             int* __restrict__ bsum, int N) {
    __shared__ int s[256];
    int i = blockIdx.x * 256 + threadIdx.x;
    int v = (i < N) ? deg[i] : 0;
    s[threadIdx.x] = v;
    __syncthreads();
    #pragma unroll
    for (int off = 1; off < 256; off <<= 1) {
        int t = (threadIdx.x >= off) ? s[threadIdx.x - off] : 0;
        __syncthreads();
        s[threadIdx.x] += t;
        __syncthreads();
    }
    if (i < N) row_off[i] = s[threadIdx.x] - v;   // exclusive
    if (threadIdx.x == 255) bsum[blockIdx.x] = s[255];
}

// ---------------- K4: scan block sums (single block, nb<=512) ----------------
__global__ void k_scan_top(int* __restrict__ bsum, int nb) {
    __shared__ int s[512];
    int v = (threadIdx.x < nb) ? bsum[threadIdx.x] : 0;
    s[threadIdx.x] = v;
    __syncthreads();
    #pragma unroll
    for (int off = 1; off < 512; off <<= 1) {
        int t = (threadIdx.x >= off) ? s[threadIdx.x - off] : 0;
        __syncthreads();
        s[threadIdx.x] += t;
        __syncthreads();
    }
    if (threadIdx.x < nb) bsum[threadIdx.x] = s[threadIdx.x] - v;   // exclusive
}

// ---------------- K5: finalize offsets, cursors, dinv ----------------
__global__ void k_finalize(int* __restrict__ row_off, int* __restrict__ cursor,
                           const int* __restrict__ bsum, const int* __restrict__ deg,
                           float* __restrict__ dinv, int N, int E) {
    int i = blockIdx.x * 256 + threadIdx.x;
    if (i < N) {
        int v = row_off[i] + bsum[i >> 8];
        row_off[i] = v;
        cursor[i] = v;
        dinv[i] = rsqrtf((float)(deg[i] + 1));   // +1 for self loop
    }
    if (i == 0) row_off[N] = E;
}

// ---------------- K6: scatter edges into CSR (atomic-path stores) ----------------
__global__ void k_scatter(const int* __restrict__ ei, int* __restrict__ cursor,
                          int* __restrict__ adj, int E) {
    int e = blockIdx.x * 256 + threadIdx.x;
    if (e < E) {
        int s = ei[e];
        int d = ei[E + e];
        int pos = atomicAdd(&cursor[d], 1);
        atomicExch(&adj[pos], s);   // coherent-point store: full-line coalescing
    }
}

// ---------------- K7: h' = (bf16(x) @ bf16(W)) * dinv[node]  (MFMA) ----------------
// Block = 256 thr = 4 waves; wave computes 16 nodes x 128 feats; block = 64 nodes.
#define WT_PITCH 136
__global__ __launch_bounds__(256) void k_gemm(const float* __restrict__ x,
                                              const float* __restrict__ W,
                                              const float* __restrict__ dinv,
                                              unsigned short* __restrict__ h, int N) {
    __shared__ unsigned short Wt[128 * WT_PITCH];   // Wt[n][k] bf16, padded
    for (int idx = threadIdx.x; idx < NIN * NOUT; idx += 256) {
        int k = idx >> 7, n = idx & 127;
        Wt[n * WT_PITCH + k] = f2bf(W[idx]);
    }
    __syncthreads();

    int wave = threadIdx.x >> 6, lane = threadIdx.x & 63;
    int node_base = blockIdx.x * 64 + wave * 16;
    if (node_base >= N) return;            // N % 16 == 0 -> active waves are full

    int c = lane & 15, quad = lane >> 4;

    // A frag: A[m=lane&15][k=quad*8+j]; convert 8 floats -> 8 bf16 per frag
    short8 a[4];
    const float* xrow = x + (size_t)(node_base + c) * NIN + quad * 8;
    #pragma unroll
    for (int kt = 0; kt < 4; kt++) {
        short8 af;
        #pragma unroll
        for (int j = 0; j < 8; j++)
            af[j] = (short)f2bf(xrow[kt * 32 + j]);
        a[kt] = af;
    }

    f32x4 acc[8];
    #pragma unroll
    for (int nt = 0; nt < 8; nt++) acc[nt] = (f32x4)(0.0f);

    #pragma unroll
    for (int nt = 0; nt < 8; nt++) {
        const unsigned short* wp = &Wt[(nt * 16 + c) * WT_PITCH + quad * 8];
        #pragma unroll
        for (int kt = 0; kt < 4; kt++) {
            short8 bfrag = *(const short8*)(wp + kt * 32);  // B[k=quad*8+j][n=lane&15]
            acc[nt] = __builtin_amdgcn_mfma_f32_16x16x32_bf16(a[kt], bfrag, acc[nt], 0, 0, 0);
        }
    }

    // D: col = lane&15, row = quad*4 + reg. Pre-scale by dinv[node] (src norm).
    float dv[4];
    #pragma unroll
    for (int r = 0; r < 4; r++)
        dv[r] = dinv[node_base + quad * 4 + r];

    #pragma unroll
    for (int nt = 0; nt < 8; nt++) {
        #pragma unroll
        for (int r = 0; r < 4; r++) {
            int node = node_base + quad * 4 + r;
            h[(size_t)node * NOUT + nt * 16 + c] = f2bf(acc[nt][r] * dv[r]);
        }
    }
}

// ---------------- K8: aggregate — one wave per destination node ----------------
// out[d] = dn * (sum_{s in N(d)} h'[s] + h'[d]) + b     (h' pre-scaled by dinv[src])
__global__ __launch_bounds__(256) void k_agg(const unsigned short* __restrict__ h,
                                             const float* __restrict__ dinv,
                                             const int* __restrict__ row_off,
                                             const int* __restrict__ adj,
                                             const float* __restrict__ bias,
                                             float* __restrict__ out, int N) {
    int wave = threadIdx.x >> 6, lane = threadIdx.x & 63;
    int node = blockIdx.x * 4 + wave;
    if (node >= N) return;

    float dn = dinv[node];
    uint pv = ((const uint*)(h + (size_t)node * NOUT))[lane];   // self (pre-scaled)
    float ax = bf2f((unsigned short)(pv & 0xFFFF));
    float ay = bf2f((unsigned short)(pv >> 16));

    int e0 = row_off[node], e1 = row_off[node + 1];
    int e = e0;
    for (; e + 3 < e1; e += 4) {                    // unroll x4 for MLP
        int s0 = adj[e], s1 = adj[e + 1], s2 = adj[e + 2], s3 = adj[e + 3];
        uint v0 = ((const uint*)(h + (size_t)s0 * NOUT))[lane];
        uint v1 = ((const uint*)(h + (size_t)s1 * NOUT))[lane];
        uint v2 = ((const uint*)(h + (size_t)s2 * NOUT))[lane];
        uint v3 = ((const uint*)(h + (size_t)s3 * NOUT))[lane];
        ax += bf2f((unsigned short)(v0 & 0xFFFF));
        ay += bf2f((unsigned short)(v0 >> 16));
        ax += bf2f((unsigned short)(v1 & 0xFFFF));
        ay += bf2f((unsigned short)(v1 >> 16));
        ax += bf2f((unsigned short)(v2 & 0xFFFF));
        ay += bf2f((unsigned short)(v2 >> 16));
        ax += bf2f((unsigned short)(v3 & 0xFFFF));
        ay += bf2f((unsigned short)(v3 >> 16));
    }
    for (; e < e1; e++) {
        int s0 = adj[e];
        uint v0 = ((const uint*)(h + (size_t)s0 * NOUT))[lane];
        ax += bf2f((unsigned short)(v0 & 0xFFFF));
        ay += bf2f((unsigned short)(v0 >> 16));
    }

    ax = ax * dn + bias[2 * lane];
    ay = ay * dn + bias[2 * lane + 1];

    float2 o = make_float2(ax, ay);
    ((float2*)(out + (size_t)node * NOUT))[lane] = o;
}

// ---------------- launch ----------------
static inline size_t align256(size_t v) { return (v + 255) & ~(size_t)255; }

extern "C" void kernel_launch(void* const* d_in, const int* in_sizes, int n_in,
                              void* d_out, int out_size, void* d_ws, size_t ws_size,
                              hipStream_t stream) {
    const float* x  = (const float*)d_in[0];     // f32 [N,128]
    const int*   ei = (const int*)d_in[1];       // int32 [2,E]
    // d_in[2] = edge_attr (f32 [E]), ignored by reference
    const float* W  = (const float*)d_in[3];     // f32 [128,128]
    const float* b  = (const float*)d_in[4];     // f32 [128]
    float*       out = (float*)d_out;            // f32 [N,128]

    int N = in_sizes[0] / NIN;
    int E = in_sizes[1] / 2;
    int nb = (N + 255) / 256;   // scan blocks (391 <= 512)

    char* ws = (char*)d_ws;
    size_t o = 0;
    int*   deg     = (int*)(ws + o);   o += align256((size_t)N * 4);
    float* dinv    = (float*)(ws + o); o += align256((size_t)N * 4);
    int*   row_off = (int*)(ws + o);   o += align256((size_t)(N + 1) * 4);
    int*   cursor  = (int*)(ws + o);   o += align256((size_t)N * 4);
    int*   bsum    = (int*)(ws + o);   o += align256((size_t)512 * 4);
    int*   adj     = (int*)(ws + o);   o += align256((size_t)E * 4);
    unsigned short* h = (unsigned short*)(ws + o); o += align256((size_t)N * NOUT * 2);
    (void)ws_size; (void)n_in; (void)out_size;

    int gN = (N + 255) / 256;
    int gE = (E + 255) / 256;

    k_zero_deg<<<gN, 256, 0, stream>>>(deg, N);
    k_count<<<gE, 256, 0, stream>>>(ei, deg, E);
    k_scan_block<<<nb, 256, 0, stream>>>(deg, row_off, bsum, N);
    k_scan_top<<<1, 512, 0, stream>>>(bsum, nb);
    k_finalize<<<gN, 256, 0, stream>>>(row_off, cursor, bsum, deg, dinv, N, E);
    k_scatter<<<gE, 256, 0, stream>>>(ei, cursor, adj, E);
    k_gemm<<<(N + 63) / 64, 256, 0, stream>>>(x, W, dinv, h, N);
    k_agg<<<(N + 3) / 4, 256, 0, stream>>>(h, dinv, row_off, adj, b, out, N);
}

// Round 4
// 337.299 us; speedup vs baseline: 1.2334x; 1.2170x over previous
//
#include <hip/hip_runtime.h>
#include <hip/hip_bf16.h>

// GCNConv: out = D^{-1/2}(A+I)D^{-1/2} X W + b
// N=100000, E=1.6M, 128->128, fp32 in/out.
// Round-4: XCD-partitioned count/scatter. Round-3 showed WRITE_SIZE=100MB on
// k_scatter (1.6M x 64B: every random 4B store wrote back a full line because
// a line's 16 entries arrive from all 8 XCDs' L2s). Now p = blockIdx%8 (the
// round-robin block->XCD mapping) handles only dst in partition p, so each adj
// region fills inside ONE XCD's L2 before writeback. Correct for any mapping.

#define NIN 128
#define NOUT 128
#define NPART 8
#define SCAT_B 256   // chunks per partition; grid = 8*SCAT_B

typedef __attribute__((ext_vector_type(8))) short short8;   // 8 bf16 (4 VGPRs)
typedef __attribute__((ext_vector_type(4))) float f32x4;    // MFMA accumulator

__device__ __forceinline__ float bf2f(unsigned short u) {
    unsigned v = ((unsigned)u) << 16;
    return __uint_as_float(v);
}
__device__ __forceinline__ unsigned short f2bf(float f) {
    unsigned u = __float_as_uint(f);
    unsigned r = 0x7FFFu + ((u >> 16) & 1u);   // RNE
    return (unsigned short)((u + r) >> 16);
}

// ---------------- K1: zero degree ----------------
__global__ void k_zero_deg(int* __restrict__ deg, int N) {
    int i = blockIdx.x * 256 + threadIdx.x;
    if (i < N) deg[i] = 0;
}

// ---------------- K2: count in-degree over dst (XCD-partitioned) ----------------
__global__ void k_count(const int* __restrict__ ei, int* __restrict__ deg,
                        int E, int N) {
    int p = blockIdx.x & (NPART - 1);   // likely XCD id (round-robin dispatch)
    int c = blockIdx.x / NPART;
    int PS = (N + NPART - 1) / NPART;
    int lo = p * PS, hi = min(N, lo + PS);
    int chunkE = (E + SCAT_B - 1) / SCAT_B;
    int e0 = c * chunkE, e1 = min(E, e0 + chunkE);
    for (int e = e0 + threadIdx.x; e < e1; e += 256) {
        int d = ei[E + e];
        if (d >= lo && d < hi) atomicAdd(&deg[d], 1);
    }
}

// ---------------- K3: per-block exclusive scan (256 elems) ----------------
__global__ void k_scan_block(const int* __restrict__ deg, int* __restrict__ row_off,
                             int* __restrict__ bsum, int N) {
    __shared__ int s[256];
    int i = blockIdx.x * 256 + threadIdx.x;
    int v = (i < N) ? deg[i] : 0;
    s[threadIdx.x] = v;
    __syncthreads();
    #pragma unroll
    for (int off = 1; off < 256; off <<= 1) {
        int t = (threadIdx.x >= off) ? s[threadIdx.x - off] : 0;
        __syncthreads();
        s[threadIdx.x] += t;
        __syncthreads();
    }
    if (i < N) row_off[i] = s[threadIdx.x] - v;   // exclusive
    if (threadIdx.x == 255) bsum[blockIdx.x] = s[255];
}

// ---------------- K4: scan block sums (single block, nb<=512) ----------------
__global__ void k_scan_top(int* __restrict__ bsum, int nb) {
    __shared__ int s[512];
    int v = (threadIdx.x < nb) ? bsum[threadIdx.x] : 0;
    s[threadIdx.x] = v;
    __syncthreads();
    #pragma unroll
    for (int off = 1; off < 512; off <<= 1) {
        int t = (threadIdx.x >= off) ? s[threadIdx.x - off] : 0;
        __syncthreads();
        s[threadIdx.x] += t;
        __syncthreads();
    }
    if (threadIdx.x < nb) bsum[threadIdx.x] = s[threadIdx.x] - v;   // exclusive
}

// ---------------- K5: finalize offsets, cursors, dinv ----------------
__global__ void k_finalize(int* __restrict__ row_off, int* __restrict__ cursor,
                           const int* __restrict__ bsum, const int* __restrict__ deg,
                           float* __restrict__ dinv, int N, int E) {
    int i = blockIdx.x * 256 + threadIdx.x;
    if (i < N) {
        int v = row_off[i] + bsum[i >> 8];
        row_off[i] = v;
        cursor[i] = v;
        dinv[i] = rsqrtf((float)(deg[i] + 1));   // +1 for self loop
    }
    if (i == 0) row_off[N] = E;
}

// ---------------- K6: scatter edges into CSR (XCD-partitioned) ----------------
__global__ void k_scatter(const int* __restrict__ ei, int* __restrict__ cursor,
                          int* __restrict__ adj, int E, int N) {
    int p = blockIdx.x & (NPART - 1);   // likely XCD id
    int c = blockIdx.x / NPART;
    int PS = (N + NPART - 1) / NPART;
    int lo = p * PS, hi = min(N, lo + PS);
    int chunkE = (E + SCAT_B - 1) / SCAT_B;
    int e0 = c * chunkE, e1 = min(E, e0 + chunkE);
    for (int e = e0 + threadIdx.x; e < e1; e += 256) {
        int d = ei[E + e];
        if (d >= lo && d < hi) {
            int s = ei[e];
            int pos = atomicAdd(&cursor[d], 1);
            adj[pos] = s;
        }
    }
}

// ---------------- K7: h' = (bf16(x) @ bf16(W)) * dinv[node]  (MFMA) ----------------
// Block = 256 thr = 4 waves; wave computes 16 nodes x 128 feats; block = 64 nodes.
#define WT_PITCH 136
__global__ __launch_bounds__(256) void k_gemm(const float* __restrict__ x,
                                              const float* __restrict__ W,
                                              const float* __restrict__ dinv,
                                              unsigned short* __restrict__ h, int N) {
    __shared__ unsigned short Wt[128 * WT_PITCH];   // Wt[n][k] bf16, padded
    for (int idx = threadIdx.x; idx < NIN * NOUT; idx += 256) {
        int k = idx >> 7, n = idx & 127;
        Wt[n * WT_PITCH + k] = f2bf(W[idx]);
    }
    __syncthreads();

    int wave = threadIdx.x >> 6, lane = threadIdx.x & 63;
    int node_base = blockIdx.x * 64 + wave * 16;
    if (node_base >= N) return;            // N % 16 == 0 -> active waves are full

    int c = lane & 15, quad = lane >> 4;

    // A frag: A[m=lane&15][k=quad*8+j]; convert 8 floats -> 8 bf16 per frag
    short8 a[4];
    const float* xrow = x + (size_t)(node_base + c) * NIN + quad * 8;
    #pragma unroll
    for (int kt = 0; kt < 4; kt++) {
        short8 af;
        #pragma unroll
        for (int j = 0; j < 8; j++)
            af[j] = (short)f2bf(xrow[kt * 32 + j]);
        a[kt] = af;
    }

    f32x4 acc[8];
    #pragma unroll
    for (int nt = 0; nt < 8; nt++) acc[nt] = (f32x4)(0.0f);

    #pragma unroll
    for (int nt = 0; nt < 8; nt++) {
        const unsigned short* wp = &Wt[(nt * 16 + c) * WT_PITCH + quad * 8];
        #pragma unroll
        for (int kt = 0; kt < 4; kt++) {
            short8 bfrag = *(const short8*)(wp + kt * 32);  // B[k=quad*8+j][n=lane&15]
            acc[nt] = __builtin_amdgcn_mfma_f32_16x16x32_bf16(a[kt], bfrag, acc[nt], 0, 0, 0);
        }
    }

    // D: col = lane&15, row = quad*4 + reg. Pre-scale by dinv[node] (src norm).
    float dv[4];
    #pragma unroll
    for (int r = 0; r < 4; r++)
        dv[r] = dinv[node_base + quad * 4 + r];

    #pragma unroll
    for (int nt = 0; nt < 8; nt++) {
        #pragma unroll
        for (int r = 0; r < 4; r++) {
            int node = node_base + quad * 4 + r;
            h[(size_t)node * NOUT + nt * 16 + c] = f2bf(acc[nt][r] * dv[r]);
        }
    }
}

// ---------------- K8: aggregate — one wave per destination node ----------------
// out[d] = dn * (sum_{s in N(d)} h'[s] + h'[d]) + b     (h' pre-scaled by dinv[src])
__global__ __launch_bounds__(256) void k_agg(const unsigned short* __restrict__ h,
                                             const float* __restrict__ dinv,
                                             const int* __restrict__ row_off,
                                             const int* __restrict__ adj,
                                             const float* __restrict__ bias,
                                             float* __restrict__ out, int N) {
    int wave = threadIdx.x >> 6, lane = threadIdx.x & 63;
    int node = blockIdx.x * 4 + wave;
    if (node >= N) return;

    float dn = dinv[node];
    uint pv = ((const uint*)(h + (size_t)node * NOUT))[lane];   // self (pre-scaled)
    float ax = bf2f((unsigned short)(pv & 0xFFFF));
    float ay = bf2f((unsigned short)(pv >> 16));

    int e0 = row_off[node], e1 = row_off[node + 1];
    int e = e0;
    for (; e + 3 < e1; e += 4) {                    // unroll x4 for MLP
        int s0 = adj[e], s1 = adj[e + 1], s2 = adj[e + 2], s3 = adj[e + 3];
        uint v0 = ((const uint*)(h + (size_t)s0 * NOUT))[lane];
        uint v1 = ((const uint*)(h + (size_t)s1 * NOUT))[lane];
        uint v2 = ((const uint*)(h + (size_t)s2 * NOUT))[lane];
        uint v3 = ((const uint*)(h + (size_t)s3 * NOUT))[lane];
        ax += bf2f((unsigned short)(v0 & 0xFFFF));
        ay += bf2f((unsigned short)(v0 >> 16));
        ax += bf2f((unsigned short)(v1 & 0xFFFF));
        ay += bf2f((unsigned short)(v1 >> 16));
        ax += bf2f((unsigned short)(v2 & 0xFFFF));
        ay += bf2f((unsigned short)(v2 >> 16));
        ax += bf2f((unsigned short)(v3 & 0xFFFF));
        ay += bf2f((unsigned short)(v3 >> 16));
    }
    for (; e < e1; e++) {
        int s0 = adj[e];
        uint v0 = ((const uint*)(h + (size_t)s0 * NOUT))[lane];
        ax += bf2f((unsigned short)(v0 & 0xFFFF));
        ay += bf2f((unsigned short)(v0 >> 16));
    }

    ax = ax * dn + bias[2 * lane];
    ay = ay * dn + bias[2 * lane + 1];

    float2 o = make_float2(ax, ay);
    ((float2*)(out + (size_t)node * NOUT))[lane] = o;
}

// ---------------- launch ----------------
static inline size_t align256(size_t v) { return (v + 255) & ~(size_t)255; }

extern "C" void kernel_launch(void* const* d_in, const int* in_sizes, int n_in,
                              void* d_out, int out_size, void* d_ws, size_t ws_size,
                              hipStream_t stream) {
    const float* x  = (const float*)d_in[0];     // f32 [N,128]
    const int*   ei = (const int*)d_in[1];       // int32 [2,E]
    // d_in[2] = edge_attr (f32 [E]), ignored by reference
    const float* W  = (const float*)d_in[3];     // f32 [128,128]
    const float* b  = (const float*)d_in[4];     // f32 [128]
    float*       out = (float*)d_out;            // f32 [N,128]

    int N = in_sizes[0] / NIN;
    int E = in_sizes[1] / 2;
    int nb = (N + 255) / 256;   // scan blocks (391 <= 512)

    char* ws = (char*)d_ws;
    size_t o = 0;
    int*   deg     = (int*)(ws + o);   o += align256((size_t)N * 4);
    float* dinv    = (float*)(ws + o); o += align256((size_t)N * 4);
    int*   row_off = (int*)(ws + o);   o += align256((size_t)(N + 1) * 4);
    int*   cursor  = (int*)(ws + o);   o += align256((size_t)N * 4);
    int*   bsum    = (int*)(ws + o);   o += align256((size_t)512 * 4);
    int*   adj     = (int*)(ws + o);   o += align256((size_t)E * 4);
    unsigned short* h = (unsigned short*)(ws + o); o += align256((size_t)N * NOUT * 2);
    (void)ws_size; (void)n_in; (void)out_size;

    int gN = (N + 255) / 256;

    k_zero_deg<<<gN, 256, 0, stream>>>(deg, N);
    k_count<<<NPART * SCAT_B, 256, 0, stream>>>(ei, deg, E, N);
    k_scan_block<<<nb, 256, 0, stream>>>(deg, row_off, bsum, N);
    k_scan_top<<<1, 512, 0, stream>>>(bsum, nb);
    k_finalize<<<gN, 256, 0, stream>>>(row_off, cursor, bsum, deg, dinv, N, E);
    k_scatter<<<NPART * SCAT_B, 256, 0, stream>>>(ei, cursor, adj, E, N);
    k_gemm<<<(N + 63) / 64, 256, 0, stream>>>(x, W, dinv, h, N);
    k_agg<<<(N + 3) / 4, 256, 0, stream>>>(h, dinv, row_off, adj, b, out, N);
}

// Round 7
// 333.400 us; speedup vs baseline: 1.2478x; 1.0117x over previous
//
#include <hip/hip_runtime.h>
#include <hip/hip_bf16.h>

// GCNConv: out = D^{-1/2}(A+I)D^{-1/2} X W + b
// N=100000, E=1.6M, 128->128, fp32 in/out.
// Round-7 (= round-6 resubmit after broker timeout): fix round-5 bug — h row
// stride is 32 uint2 (256B), not 16.
// k_agg: 2 edges per wave (32 lanes/row, uint2/lane), unroll x4 => 8 rows in
// flight, shfl_xor(32) combine, NT float4 stores. scan_top merged into finalize;
// zero_deg via hipMemsetAsync. Count/scatter XCD-partitioned (round-4 win).

#define NIN 128
#define NOUT 128
#define NPART 8
#define SCAT_B 256   // chunks per partition; grid = 8*SCAT_B

typedef __attribute__((ext_vector_type(8))) short short8;   // 8 bf16 (4 VGPRs)
typedef __attribute__((ext_vector_type(4))) float f32x4;    // MFMA accumulator

__device__ __forceinline__ float bf2f(unsigned short u) {
    unsigned v = ((unsigned)u) << 16;
    return __uint_as_float(v);
}
__device__ __forceinline__ unsigned short f2bf(float f) {
    unsigned u = __float_as_uint(f);
    unsigned r = 0x7FFFu + ((u >> 16) & 1u);   // RNE
    return (unsigned short)((u + r) >> 16);
}

// ---------------- K2: count in-degree over dst (XCD-partitioned) ----------------
__global__ void k_count(const int* __restrict__ ei, int* __restrict__ deg,
                        int E, int N) {
    int p = blockIdx.x & (NPART - 1);   // likely XCD id (round-robin dispatch)
    int c = blockIdx.x / NPART;
    int PS = (N + NPART - 1) / NPART;
    int lo = p * PS, hi = min(N, lo + PS);
    int chunkE = (E + SCAT_B - 1) / SCAT_B;
    int e0 = c * chunkE, e1 = min(E, e0 + chunkE);
    for (int e = e0 + threadIdx.x; e < e1; e += 256) {
        int d = ei[E + e];
        if (d >= lo && d < hi) atomicAdd(&deg[d], 1);
    }
}

// ---------------- K3: per-block exclusive scan (256 elems) ----------------
__global__ void k_scan_block(const int* __restrict__ deg, int* __restrict__ row_off,
                             int* __restrict__ bsum, int N) {
    __shared__ int s[256];
    int i = blockIdx.x * 256 + threadIdx.x;
    int v = (i < N) ? deg[i] : 0;
    s[threadIdx.x] = v;
    __syncthreads();
    #pragma unroll
    for (int off = 1; off < 256; off <<= 1) {
        int t = (threadIdx.x >= off) ? s[threadIdx.x - off] : 0;
        __syncthreads();
        s[threadIdx.x] += t;
        __syncthreads();
    }
    if (i < N) row_off[i] = s[threadIdx.x] - v;   // exclusive
    if (threadIdx.x == 255) bsum[blockIdx.x] = s[255];
}

// ---------------- K5: finalize offsets, cursors, dinv (+ own bsum prefix) ----------------
__global__ void k_finalize(int* __restrict__ row_off, int* __restrict__ cursor,
                           const int* __restrict__ bsum, const int* __restrict__ deg,
                           float* __restrict__ dinv, int N, int E) {
    __shared__ int red[256];
    int acc = 0;
    for (int t = threadIdx.x; t < (int)blockIdx.x; t += 256) acc += bsum[t];
    red[threadIdx.x] = acc;
    __syncthreads();
    #pragma unroll
    for (int off = 128; off > 0; off >>= 1) {
        if (threadIdx.x < off) red[threadIdx.x] += red[threadIdx.x + off];
        __syncthreads();
    }
    int pref = red[0];

    int i = blockIdx.x * 256 + threadIdx.x;
    if (i < N) {
        int v = row_off[i] + pref;
        row_off[i] = v;
        cursor[i] = v;
        dinv[i] = rsqrtf((float)(deg[i] + 1));   // +1 for self loop
    }
    if (blockIdx.x == 0 && threadIdx.x == 0) row_off[N] = E;
}

// ---------------- K6: scatter edges into CSR (XCD-partitioned) ----------------
__global__ void k_scatter(const int* __restrict__ ei, int* __restrict__ cursor,
                          int* __restrict__ adj, int E, int N) {
    int p = blockIdx.x & (NPART - 1);   // likely XCD id
    int c = blockIdx.x / NPART;
    int PS = (N + NPART - 1) / NPART;
    int lo = p * PS, hi = min(N, lo + PS);
    int chunkE = (E + SCAT_B - 1) / SCAT_B;
    int e0 = c * chunkE, e1 = min(E, e0 + chunkE);
    for (int e = e0 + threadIdx.x; e < e1; e += 256) {
        int d = ei[E + e];
        if (d >= lo && d < hi) {
            int s = ei[e];
            int pos = atomicAdd(&cursor[d], 1);
            adj[pos] = s;
        }
    }
}

// ---------------- K7: h' = (bf16(x) @ bf16(W)) * dinv[node]  (MFMA) ----------------
// Block = 256 thr = 4 waves; wave computes 16 nodes x 128 feats; block = 64 nodes.
#define WT_PITCH 136
__global__ __launch_bounds__(256) void k_gemm(const float* __restrict__ x,
                                              const float* __restrict__ W,
                                              const float* __restrict__ dinv,
                                              unsigned short* __restrict__ h, int N) {
    __shared__ unsigned short Wt[128 * WT_PITCH];   // Wt[n][k] bf16, padded
    for (int idx = threadIdx.x; idx < NIN * NOUT; idx += 256) {
        int k = idx >> 7, n = idx & 127;
        Wt[n * WT_PITCH + k] = f2bf(W[idx]);
    }
    __syncthreads();

    int wave = threadIdx.x >> 6, lane = threadIdx.x & 63;
    int node_base = blockIdx.x * 64 + wave * 16;
    if (node_base >= N) return;            // N % 16 == 0 -> active waves are full

    int c = lane & 15, quad = lane >> 4;

    // A frag: A[m=lane&15][k=quad*8+j]; float4 x2 loads (32B aligned), cvt to bf16
    short8 a[4];
    const float4* xrow = (const float4*)(x + (size_t)(node_base + c) * NIN + quad * 8);
    #pragma unroll
    for (int kt = 0; kt < 4; kt++) {
        float4 f0 = xrow[kt * 8];
        float4 f1 = xrow[kt * 8 + 1];
        short8 af;
        af[0] = (short)f2bf(f0.x); af[1] = (short)f2bf(f0.y);
        af[2] = (short)f2bf(f0.z); af[3] = (short)f2bf(f0.w);
        af[4] = (short)f2bf(f1.x); af[5] = (short)f2bf(f1.y);
        af[6] = (short)f2bf(f1.z); af[7] = (short)f2bf(f1.w);
        a[kt] = af;
    }

    f32x4 acc[8];
    #pragma unroll
    for (int nt = 0; nt < 8; nt++) acc[nt] = (f32x4)(0.0f);

    #pragma unroll
    for (int nt = 0; nt < 8; nt++) {
        const unsigned short* wp = &Wt[(nt * 16 + c) * WT_PITCH + quad * 8];
        #pragma unroll
        for (int kt = 0; kt < 4; kt++) {
            short8 bfrag = *(const short8*)(wp + kt * 32);  // B[k=quad*8+j][n=lane&15]
            acc[nt] = __builtin_amdgcn_mfma_f32_16x16x32_bf16(a[kt], bfrag, acc[nt], 0, 0, 0);
        }
    }

    // D: col = lane&15, row = quad*4 + reg. Pre-scale by dinv[node] (src norm).
    float dv[4];
    #pragma unroll
    for (int r = 0; r < 4; r++)
        dv[r] = dinv[node_base + quad * 4 + r];

    #pragma unroll
    for (int nt = 0; nt < 8; nt++) {
        #pragma unroll
        for (int r = 0; r < 4; r++) {
            int node = node_base + quad * 4 + r;
            h[(size_t)node * NOUT + nt * 16 + c] = f2bf(acc[nt][r] * dv[r]);
        }
    }
}

// ---------------- K8: aggregate — one wave per dst node, 2 edges/instr ----------------
// out[d] = dn * (sum_{s in N(d)} h'[s] + h'[d]) + b     (h' pre-scaled by dinv[src])
// Lane layout: half = lane>>5 processes edge e+half; sub = lane&31 owns feats
// 4*sub..4*sub+3 (uint2 = 4 bf16; row = 32 uint2). shfl_xor(32) combine.
__global__ __launch_bounds__(256) void k_agg(const unsigned short* __restrict__ h,
                                             const float* __restrict__ dinv,
                                             const int* __restrict__ row_off,
                                             const int* __restrict__ adj,
                                             const float* __restrict__ bias,
                                             float* __restrict__ out, int N) {
    int wave = threadIdx.x >> 6, lane = threadIdx.x & 63;
    int half = lane >> 5, sub = lane & 31;
    int node = blockIdx.x * 4 + wave;
    if (node >= N) return;

    float dn = dinv[node];
    int e0 = row_off[node], e1 = row_off[node + 1];

    const uint2* hp = (const uint2*)h;   // row s = hp[s*32 + sub]  (256B row)
    float a0 = 0.f, a1 = 0.f, a2 = 0.f, a3 = 0.f;

    // first item: half0 -> self row, half1 -> first edge (if any)
    {
        int s = half ? ((e0 < e1) ? adj[e0] : node) : node;
        uint2 v = hp[(size_t)s * 32 + sub];
        if (!half || (e0 < e1)) {
            a0 += bf2f((unsigned short)(v.x & 0xFFFF));
            a1 += bf2f((unsigned short)(v.x >> 16));
            a2 += bf2f((unsigned short)(v.y & 0xFFFF));
            a3 += bf2f((unsigned short)(v.y >> 16));
        }
    }

    int e = e0 + 1;
    for (; e + 7 < e1; e += 8) {         // 8 edges: 4 load-instrs, 8 rows in flight
        #pragma unroll
        for (int k = 0; k < 4; k++) {
            int s = adj[e + 2 * k + half];
            uint2 v = hp[(size_t)s * 32 + sub];
            a0 += bf2f((unsigned short)(v.x & 0xFFFF));
            a1 += bf2f((unsigned short)(v.x >> 16));
            a2 += bf2f((unsigned short)(v.y & 0xFFFF));
            a3 += bf2f((unsigned short)(v.y >> 16));
        }
    }
    for (; e + 1 < e1; e += 2) {
        int s = adj[e + half];
        uint2 v = hp[(size_t)s * 32 + sub];
        a0 += bf2f((unsigned short)(v.x & 0xFFFF));
        a1 += bf2f((unsigned short)(v.x >> 16));
        a2 += bf2f((unsigned short)(v.y & 0xFFFF));
        a3 += bf2f((unsigned short)(v.y >> 16));
    }
    if (e < e1) {                         // odd leftover: half0 only
        int s = adj[e];
        uint2 v = hp[(size_t)s * 32 + sub];
        if (!half) {
            a0 += bf2f((unsigned short)(v.x & 0xFFFF));
            a1 += bf2f((unsigned short)(v.x >> 16));
            a2 += bf2f((unsigned short)(v.y & 0xFFFF));
            a3 += bf2f((unsigned short)(v.y >> 16));
        }
    }

    // combine halves
    a0 += __shfl_xor(a0, 32);
    a1 += __shfl_xor(a1, 32);
    a2 += __shfl_xor(a2, 32);
    a3 += __shfl_xor(a3, 32);

    if (!half) {
        float4 b4 = ((const float4*)bias)[sub];
        f32x4 o;
        o[0] = a0 * dn + b4.x;
        o[1] = a1 * dn + b4.y;
        o[2] = a2 * dn + b4.z;
        o[3] = a3 * dn + b4.w;
        __builtin_nontemporal_store(o, (f32x4*)(out + (size_t)node * NOUT) + sub);
    }
}

// ---------------- launch ----------------
static inline size_t align256(size_t v) { return (v + 255) & ~(size_t)255; }

extern "C" void kernel_launch(void* const* d_in, const int* in_sizes, int n_in,
                              void* d_out, int out_size, void* d_ws, size_t ws_size,
                              hipStream_t stream) {
    const float* x  = (const float*)d_in[0];     // f32 [N,128]
    const int*   ei = (const int*)d_in[1];       // int32 [2,E]
    // d_in[2] = edge_attr (f32 [E]), ignored by reference
    const float* W  = (const float*)d_in[3];     // f32 [128,128]
    const float* b  = (const float*)d_in[4];     // f32 [128]
    float*       out = (float*)d_out;            // f32 [N,128]

    int N = in_sizes[0] / NIN;
    int E = in_sizes[1] / 2;
    int nb = (N + 255) / 256;   // scan blocks (391)

    char* ws = (char*)d_ws;
    size_t o = 0;
    int*   deg     = (int*)(ws + o);   o += align256((size_t)N * 4);
    float* dinv    = (float*)(ws + o); o += align256((size_t)N * 4);
    int*   row_off = (int*)(ws + o);   o += align256((size_t)(N + 1) * 4);
    int*   cursor  = (int*)(ws + o);   o += align256((size_t)N * 4);
    int*   bsum    = (int*)(ws + o);   o += align256((size_t)512 * 4);
    int*   adj     = (int*)(ws + o);   o += align256((size_t)E * 4);
    unsigned short* h = (unsigned short*)(ws + o); o += align256((size_t)N * NOUT * 2);
    (void)ws_size; (void)n_in; (void)out_size;

    hipMemsetAsync(deg, 0, (size_t)N * 4, stream);
    k_count<<<NPART * SCAT_B, 256, 0, stream>>>(ei, deg, E, N);
    k_scan_block<<<nb, 256, 0, stream>>>(deg, row_off, bsum, N);
    k_finalize<<<nb, 256, 0, stream>>>(row_off, cursor, bsum, deg, dinv, N, E);
    k_scatter<<<NPART * SCAT_B, 256, 0, stream>>>(ei, cursor, adj, E, N);
    k_gemm<<<(N + 63) / 64, 256, 0, stream>>>(x, W, dinv, h, N);
    k_agg<<<(N + 3) / 4, 256, 0, stream>>>(h, dinv, row_off, adj, b, out, N);
}